// Round 13
// baseline (247.968 us; speedup 1.0000x reference)
//
#include <hip/hip_runtime.h>
#include <math.h>

// ---- problem constants ----
static constexpr int B_  = 4;
static constexpr int C_  = 64;
static constexpr int H_  = 96;
static constexpr int W_  = 320;
static constexpr int HW  = H_ * W_;          // 30720
static constexpr int RCH = 16;               // RC = C/4
static constexpr int D_  = 48;
static constexpr int NG  = 8;                // groupnorm groups
static constexpr int CPG = RCH / NG;         // 2 channels per group
static constexpr float EPS_ = 1e-5f;
static constexpr int APX = 322;              // abf padded px count (w = -1..320)

typedef __attribute__((ext_vector_type(8))) short short8;
typedef __attribute__((ext_vector_type(4))) float f32x4;
typedef __attribute__((ext_vector_type(4))) unsigned int u32x4;
typedef __attribute__((ext_vector_type(4))) unsigned short u16x4;

__device__ __forceinline__ float elu1(float x) { return x > 0.f ? x : __expf(x) - 1.f; }
__device__ __forceinline__ float sigm(float x) { return 1.f / (1.f + __expf(-x)); }
__device__ __forceinline__ unsigned bf16rne(float f) {
    unsigned u = __builtin_bit_cast(unsigned, f);
    u += 0x7fffu + ((u >> 16) & 1u);
    return u >> 16;
}
__device__ __forceinline__ float bf2f(unsigned short u) {
    unsigned v = ((unsigned)u) << 16;
    return __builtin_bit_cast(float, v);
}
__device__ __forceinline__ void gload16(const void* g, void* l) {
    __builtin_amdgcn_global_load_lds((const __attribute__((address_space(1))) unsigned int*)g,
                                     (__attribute__((address_space(3))) unsigned int*)l, 16, 0, 0);
}

// ---------- 0. merged weight prep: blocks 0..35 = MFMA wpack, block 36 = conv repack + ymean zero ----------
__global__ __launch_bounds__(256) void k_wprep(
    const float* __restrict__ qw, const float* __restrict__ kw, const float* __restrict__ law,
    const float* __restrict__ fw,
    float* __restrict__ qwp, float* __restrict__ kwp, float* __restrict__ lawp,
    unsigned short* __restrict__ wpack, float* __restrict__ ymean)
{
    int bi = blockIdx.x;
    int t = threadIdx.x;
    if (bi == 36) {
        if (t < B_ * C_) ymean[t] = 0.f;
        for (int i = t; i < RCH * C_; i += 256) {
            int c = i >> 4, r = i & 15;
            qwp[i] = qw[r * C_ + c];
            kwp[i] = kw[r * C_ + c];
        }
        for (int i = t; i < RCH * RCH * 9; i += 256) {
            int co = i & 15, rest = i >> 4;   // rest = ci*9 + tap
            int ci = rest / 9, tap = rest % 9;
            lawp[i] = law[(co * RCH + ci) * 9 + tap];
        }
        return;
    }
    int tap = bi >> 2, kblk = bi & 3;
    int kh = tap / 3, kw2 = tap % 3;
    int ct = t >> 6, l = t & 63;
    int co = ct * 16 + (l & 15);
    int ci0 = kblk * 32 + ((l >> 4) & 3) * 8;
    unsigned short v[8];
#pragma unroll
    for (int j = 0; j < 8; j++) {
        int ci = ci0 + j;
        float f = (ci < 112) ? fw[((size_t)(co * 112 + ci)) * 9 + kh * 3 + kw2] : 0.f;
        v[j] = (unsigned short)bf16rne(f);
    }
    *reinterpret_cast<short8*>(wpack + ((size_t)bi * 256 + t) * 8) = *reinterpret_cast<short8*>(v);
}

// ---------- 1. 1x1 conv: left->qraw, right->kraw. SGPR weights, 4px/thread float4, full unroll ----------
__global__ __launch_bounds__(256) void k_conv_qk(
    const float* __restrict__ left, const float* __restrict__ right,
    const float* __restrict__ qwp, const float* __restrict__ kwp,
    float* __restrict__ qraw, float* __restrict__ kraw)
{
    int idx = blockIdx.x * 256 + threadIdx.x;      // 240*256 threads, 4 px each
    int half = idx / (B_ * HW / 4);                // 0 = q (left), 1 = k (right); block-uniform
    int r0 = idx - half * (B_ * HW / 4);
    int b = r0 / (HW / 4), p4 = r0 - b * (HW / 4);
    int p = p4 * 4;
    const float* src = (half ? right : left) + (size_t)b * C_ * HW + p;
    const float* wp  = half ? kwp : qwp;
    float* dst = (half ? kraw : qraw) + (size_t)b * RCH * HW + p;
    float4 acc[RCH];
#pragma unroll
    for (int r = 0; r < RCH; r++) acc[r] = make_float4(0.f, 0.f, 0.f, 0.f);
#pragma unroll
    for (int c = 0; c < C_; c++) {                 // 64 independent 16B loads pipeline
        float4 v = *reinterpret_cast<const float4*>(src + (size_t)c * HW);
        const float* wrow = wp + c * RCH;          // uniform -> s_load operands
#pragma unroll
        for (int r = 0; r < RCH; r++) {
            acc[r].x += v.x * wrow[r];
            acc[r].y += v.y * wrow[r];
            acc[r].z += v.z * wrow[r];
            acc[r].w += v.w * wrow[r];
        }
    }
#pragma unroll
    for (int r = 0; r < RCH; r++)
        *reinterpret_cast<float4*>(dst + (size_t)r * HW) = acc[r];
}

// ---------- 2. group-norm stats for q AND k in one launch: blocks 0..31 q, 32..63 k ----------
__global__ __launch_bounds__(256) void k_gn_stats2(const float* __restrict__ qsrc,
    const float* __restrict__ ksrc, float* __restrict__ stats)
{
    int z = blockIdx.x;
    const float* src = (z < 32) ? qsrc : ksrc;
    int zz = (z < 32) ? z : z - 32;
    int b = zz / NG, g = zz % NG;
    const float4* base = (const float4*)(src + ((size_t)b * RCH + g * CPG) * HW);
    float s = 0.f, ss = 0.f;
    for (int i = threadIdx.x; i < CPG * HW / 4; i += 256) {
        float4 v = base[i];
        s  += v.x + v.y + v.z + v.w;
        ss += v.x * v.x + v.y * v.y + v.z * v.z + v.w * v.w;
    }
    __shared__ float rs[256], rq[256];
    rs[threadIdx.x] = s; rq[threadIdx.x] = ss; __syncthreads();
    for (int off = 128; off > 0; off >>= 1) {
        if (threadIdx.x < off) { rs[threadIdx.x] += rs[threadIdx.x + off]; rq[threadIdx.x] += rq[threadIdx.x + off]; }
        __syncthreads();
    }
    if (threadIdx.x == 0) {
        float inv = 1.f / (float)(CPG * HW);
        float m = rs[0] * inv;
        float var = rq[0] * inv - m * m;
        stats[z * 2 + 0] = m;
        stats[z * 2 + 1] = rsqrtf(var + EPS_);
    }
}

// ---------- 2b. group-norm stats (single tensor, for lraw) ----------
__global__ __launch_bounds__(256) void k_gn_stats(const float* __restrict__ src, float* __restrict__ stats)
{
    int b = blockIdx.x / NG, g = blockIdx.x % NG;
    const float4* base = (const float4*)(src + ((size_t)b * RCH + g * CPG) * HW);
    float s = 0.f, ss = 0.f;
    for (int i = threadIdx.x; i < CPG * HW / 4; i += 256) {
        float4 v = base[i];
        s  += v.x + v.y + v.z + v.w;
        ss += v.x * v.x + v.y * v.y + v.z * v.z + v.w * v.w;
    }
    __shared__ float rs[256], rq[256];
    rs[threadIdx.x] = s; rq[threadIdx.x] = ss; __syncthreads();
    for (int off = 128; off > 0; off >>= 1) {
        if (threadIdx.x < off) { rs[threadIdx.x] += rs[threadIdx.x + off]; rq[threadIdx.x] += rq[threadIdx.x + off]; }
        __syncthreads();
    }
    if (threadIdx.x == 0) {
        float inv = 1.f / (float)(CPG * HW);
        float m = rs[0] * inv;
        float var = rq[0] * inv - m * m;
        stats[blockIdx.x * 2 + 0] = m;
        stats[blockIdx.x * 2 + 1] = rsqrtf(var + EPS_);
    }
}

// ---------- 3. GN apply + elu, in place (for q), float4 ----------
__global__ __launch_bounds__(256) void k_gn_apply(float* __restrict__ x, const float* __restrict__ stats,
    const float* __restrict__ gam, const float* __restrict__ bet)
{
    int idx4 = blockIdx.x * 256 + threadIdx.x;     // B_*RCH*HW/4 threads
    int b = idx4 / (RCH * HW / 4);
    int rc = (idx4 / (HW / 4)) % RCH;
    int g = rc >> 1;
    float m = stats[(b * NG + g) * 2], is = stats[(b * NG + g) * 2 + 1];
    float ga = gam[rc] * is, be = bet[rc] - m * is * gam[rc];
    float4 v = ((const float4*)x)[idx4];
    v.x = elu1(v.x * ga + be); v.y = elu1(v.y * ga + be);
    v.z = elu1(v.z * ga + be); v.w = elu1(v.w * ga + be);
    ((float4*)x)[idx4] = v;
}

// ---------- 4. km = mean over channels of elu(GN(kraw)) ----------
__global__ __launch_bounds__(256) void k_km(const float* __restrict__ kraw, const float* __restrict__ stats,
    const float* __restrict__ gam, const float* __restrict__ bet, float* __restrict__ km)
{
    int idx = blockIdx.x * 256 + threadIdx.x;      // B_*HW
    int b = idx / HW, p = idx - b * HW;
    float s = 0.f;
#pragma unroll
    for (int rc = 0; rc < RCH; rc++) {
        int g = rc >> 1;
        float m = stats[(b * NG + g) * 2], is = stats[(b * NG + g) * 2 + 1];
        float v = (kraw[((size_t)b * RCH + rc) * HW + p] - m) * is * gam[rc] + bet[rc];
        s += elu1(v);
    }
    km[idx] = s * (1.f / (float)RCH);
}

// ---------- 5. per-row mean over HW (gp), float4 ----------
__global__ __launch_bounds__(256) void k_rowmean(const float* __restrict__ src, float* __restrict__ out)
{
    const float4* base = (const float4*)(src + (size_t)blockIdx.x * HW);
    float s = 0.f;
    for (int p = threadIdx.x; p < HW / 4; p += 256) {
        float4 v = base[p];
        s += v.x + v.y + v.z + v.w;
    }
    __shared__ float red[256];
    red[threadIdx.x] = s; __syncthreads();
    for (int off = 128; off > 0; off >>= 1) {
        if (threadIdx.x < off) red[threadIdx.x] += red[threadIdx.x + off];
        __syncthreads();
    }
    if (threadIdx.x == 0) out[blockIdx.x] = red[0] * (1.f / (float)HW);
}

// ---------- 6. gfeat MLP + fold into attn-hidden bias: gbias[b,o] (gp holds MEANS) ----------
__global__ __launch_bounds__(64) void k_gfeat(const float* __restrict__ gp,
    const float* __restrict__ gaw1, const float* __restrict__ gab1,
    const float* __restrict__ gaw2, const float* __restrict__ gab2,
    const float* __restrict__ afw1, const float* __restrict__ afb1,
    float* __restrict__ gbias)
{
    __shared__ float g1[B_ * 8], gf[B_ * RCH];
    int t = threadIdx.x;
    if (t < B_ * 8) {
        int b = t >> 3, o = t & 7;
        float a = gab1[o];
        for (int i = 0; i < RCH; i++) a += gaw1[o * RCH + i] * gp[b * RCH + i];
        g1[b * 8 + o] = elu1(a);
    }
    __syncthreads();
    {
        int b = t >> 4, o = t & 15;
        float a = gab2[o];
        for (int i = 0; i < 8; i++) a += gaw2[o * 8 + i] * g1[b * 8 + i];
        gf[t] = a;
    }
    __syncthreads();
    {
        int b = t >> 4, o = t & 15;
        float a = afb1[o];
        for (int i = 0; i < RCH; i++) a += afw1[o * 2 * RCH + i] * gf[b * RCH + i];
        gbias[t] = a;
    }
}

// ---------- 7. 3x3 conv q -> lraw (zero pad, bias). SGPR weights, full unroll ----------
__global__ __launch_bounds__(256) void k_conv_la(const float* __restrict__ q,
    const float* __restrict__ lawp, const float* __restrict__ lab, float* __restrict__ lraw)
{
    int idx = blockIdx.x * 256 + threadIdx.x;      // B_*HW
    int b = idx / HW, p = idx - b * HW;
    int h = p / W_, w = p - h * W_;
    float acc[RCH];
#pragma unroll
    for (int co = 0; co < RCH; co++) acc[co] = lab[co];
#pragma unroll
    for (int ci = 0; ci < RCH; ci++) {
        const float* qb = q + ((size_t)b * RCH + ci) * HW;
#pragma unroll
        for (int kh = 0; kh < 3; kh++) {
            int hh = h + kh - 1;
            if (hh < 0 || hh >= H_) continue;
            float a0 = (w - 1 >= 0) ? qb[hh * W_ + w - 1] : 0.f;
            float a1 = qb[hh * W_ + w];
            float a2 = (w + 1 < W_) ? qb[hh * W_ + w + 1] : 0.f;
            const float* wp0 = lawp + (ci * 9 + kh * 3) * RCH;   // uniform -> s_load
#pragma unroll
            for (int co = 0; co < RCH; co++)
                acc[co] += a0 * wp0[co] + a1 * wp0[RCH + co] + a2 * wp0[2 * RCH + co];
        }
    }
#pragma unroll
    for (int co = 0; co < RCH; co++) lraw[((size_t)b * RCH + co) * HW + p] = acc[co];
}

// ---------- 8. fused vol: one block per (b,h) row; km row in LDS; weights via SGPR (r13) ----------
__global__ __launch_bounds__(320) void k_vol(const float* __restrict__ lraw,
    const float* __restrict__ stats, const float* __restrict__ lg, const float* __restrict__ lb,
    const float* __restrict__ gbias, const float* __restrict__ afw1,
    const float* __restrict__ afw2, const float* __restrict__ afb2,
    const float* __restrict__ km, const float* __restrict__ directs, float* __restrict__ vol)
{
    __shared__ float kms[W_];
    int blk = blockIdx.x;                 // B_*H_ = 384
    int b = blk / H_, h = blk - b * H_;
    int t = threadIdx.x;                  // 0..319 = w
    kms[t] = km[(size_t)b * HW + h * W_ + t];
    __syncthreads();
    int w = t, p = h * W_ + w;
    float lf[RCH];
#pragma unroll
    for (int rc = 0; rc < RCH; rc++) {
        int g = rc >> 1;
        float m = stats[(b * NG + g) * 2], is = stats[(b * NG + g) * 2 + 1];
        lf[rc] = elu1((lraw[((size_t)b * RCH + rc) * HW + p] - m) * is * lg[rc] + lb[rc]);
    }
    float hid[RCH];
#pragma unroll
    for (int o = 0; o < RCH; o++) {
        float a = gbias[b * RCH + o];
        const float* wrow = afw1 + o * 2 * RCH + RCH;   // uniform -> s_load
#pragma unroll
        for (int i = 0; i < RCH; i++) a += wrow[i] * lf[i];
        hid[o] = elu1(a);
    }
    float dir = directs[b];
    for (int d = 0; d < D_; d++) {
        float a = afb2[d];                               // uniform -> s_load
        const float* w2row = afw2 + d * RCH;             // uniform -> s_load
#pragma unroll
        for (int o = 0; o < RCH; o++) a += w2row[o] * hid[o];
        float s = sigm(a);
        float shift = ((float)d / 160.f) * dir * (float)(W_ - 1);
        float pos = (float)w + shift;
        float x0 = floorf(pos);
        float f = pos - x0;
        float c0 = fminf(fmaxf(x0, 0.f), (float)(W_ - 1));
        float c1 = fminf(fmaxf(x0 + 1.f, 0.f), (float)(W_ - 1));
        int i0 = (int)c0, i1 = (int)c1;
        float wv = kms[i0] * (1.f - f) + kms[i1] * f;
        vol[((size_t)(b * D_ + d)) * HW + p] = wv * s;
    }
}

// ---------- 9. depthwise 3x3 + elu, 4 px/thread (writes into ncost region as scratch) ----------
__global__ __launch_bounds__(256) void k_dw(const float* __restrict__ vol,
    const float* __restrict__ wgt, const float* __restrict__ bias, float* __restrict__ dwout)
{
    int idx = blockIdx.x * 256 + threadIdx.x;      // B_*D_*HW/4
    int p4 = idx % (HW / 4);
    int d  = (idx / (HW / 4)) % D_;
    int b  = idx / (D_ * HW / 4);
    int h = p4 / (W_ / 4), w = (p4 % (W_ / 4)) * 4;
    const float* vb = vol + ((size_t)(b * D_ + d)) * HW;
    float wz[9];
#pragma unroll
    for (int i = 0; i < 9; i++) wz[i] = wgt[d * 9 + i];
    float bv = bias[d];
    float acc[4] = {bv, bv, bv, bv};
#pragma unroll
    for (int r = 0; r < 3; r++) {
        int hh = h + r - 1;
        if (hh < 0 || hh >= H_) continue;
        const float* row = vb + hh * W_;
        float4 c = *(const float4*)(row + w);
        float in6[6];
        in6[0] = (w > 0) ? row[w - 1] : 0.f;
        in6[1] = c.x; in6[2] = c.y; in6[3] = c.z; in6[4] = c.w;
        in6[5] = (w + 4 < W_) ? row[w + 4] : 0.f;
#pragma unroll
        for (int j = 0; j < 4; j++)
            acc[j] += in6[j] * wz[r * 3] + in6[j + 1] * wz[r * 3 + 1] + in6[j + 2] * wz[r * 3 + 2];
    }
    float4 o;
    o.x = elu1(acc[0]); o.y = elu1(acc[1]); o.z = elu1(acc[2]); o.w = elu1(acc[3]);
    ((float4*)dwout)[idx] = o;
}

// ---------- 9b. prep: abf[b][h][322][120ci] bf16 — left channels (dw 0..31) + zero pad (dw 56..59) ----------
__global__ __launch_bounds__(256) void k_prep(const float* __restrict__ left, unsigned int* __restrict__ abf)
{
    int idx = blockIdx.x * 256 + threadIdx.x;      // B_*H_*APX = 123,648 exactly
    int px = idx % APX;
    int bh = idx / APX;
    int b = bh / H_, h = bh % H_;
    int w = px - 1;
    w = w < 0 ? -w : (w >= W_ ? 2 * W_ - 2 - w : w);
    const float* src = left + (size_t)b * C_ * HW + h * W_ + w;
    unsigned int* dst = abf + (size_t)idx * 60;
#pragma unroll
    for (int q4 = 0; q4 < 8; q4++) {
        u32x4 t;
#pragma unroll
        for (int z = 0; z < 4; z++) {
            int ci = (q4 * 4 + z) * 2;
            float f0 = src[(size_t)ci * HW];
            float f1 = src[(size_t)(ci + 1) * HW];
            t[z] = bf16rne(f0) | (bf16rne(f1) << 16);
        }
        *reinterpret_cast<u32x4*>(dst + q4 * 4) = t;
    }
    *reinterpret_cast<u32x4*>(dst + 56) = (u32x4){0u, 0u, 0u, 0u};
}

// ---------- 10. 1x1 48->48 + softmax, IN PLACE on ncost; weights via SGPR (r13); writes abf dw 32..55 ----------
__global__ __launch_bounds__(256) void k_rpw(float* __restrict__ ncost,
    const float* __restrict__ wgt, const float* __restrict__ bias,
    unsigned int* __restrict__ abf)
{
    int idx = blockIdx.x * 256 + threadIdx.x;      // B_*HW
    int b = idx / HW, p = idx - b * HW;
    int h = p / W_, w = p - h * W_;
    float v[D_];
#pragma unroll
    for (int i = 0; i < D_; i++) v[i] = ncost[((size_t)(b * D_ + i)) * HW + p];
    float cst[D_];
    float mx = -1e30f;
#pragma unroll
    for (int d = 0; d < D_; d++) {
        float a = bias[d];                              // uniform -> s_load
        const float4* wrow = (const float4*)(wgt + d * D_);   // uniform -> s_load_dwordx4
#pragma unroll
        for (int i4 = 0; i4 < D_ / 4; i4++) {
            float4 wv = wrow[i4];
            a += wv.x * v[i4 * 4 + 0] + wv.y * v[i4 * 4 + 1]
               + wv.z * v[i4 * 4 + 2] + wv.w * v[i4 * 4 + 3];
        }
        cst[d] = a; mx = fmaxf(mx, a);
    }
    float s = 0.f;
#pragma unroll
    for (int d = 0; d < D_; d++) { float e = __expf(cst[d] - mx); cst[d] = e; s += e; }
    float inv = 1.f / s;
#pragma unroll
    for (int d = 0; d < D_; d++) {
        cst[d] *= inv;
        ncost[((size_t)(b * D_ + d)) * HW + p] = cst[d];
    }
    u32x4 pk[6];
#pragma unroll
    for (int q4 = 0; q4 < 6; q4++)
#pragma unroll
        for (int z = 0; z < 4; z++) {
            int d = (q4 * 4 + z) * 2;
            pk[q4][z] = bf16rne(cst[d]) | (bf16rne(cst[d + 1]) << 16);
        }
    size_t bh322 = (size_t)(b * H_ + h) * APX;
    unsigned int* dst = abf + (bh322 + (w + 1)) * 60 + 32;
#pragma unroll
    for (int q4 = 0; q4 < 6; q4++) *reinterpret_cast<u32x4*>(dst + q4 * 4) = pk[q4];
    if (w == 1 || w == W_ - 2) {
        unsigned int* dst2 = abf + (bh322 + (w == 1 ? 0 : APX - 1)) * 60 + 32;
#pragma unroll
        for (int q4 = 0; q4 < 6; q4++) *reinterpret_cast<u32x4*>(dst2 + q4 * 4) = pk[q4];
    }
}

// ---------- 11. fused 3x3 conv 112->64, reflect pad, bf16 MFMA implicit GEMM ----------
static constexpr int TPX    = 80;                  // output px per block
static constexpr int LPXC   = TPX + 2;             // 82 staged px per plane
static constexpr int LROWB  = 240;                 // bytes per px (120 bf16)
static constexpr int LPLANB = LPXC * LROWB;        // 19680 B per input row
static constexpr int NPT    = TPX / 16;            // 5 px-tiles per wave
__global__ __launch_bounds__(256, 1) void k_fused_mfma(
    const unsigned int* __restrict__ abf,
    const unsigned short* __restrict__ wpack, const float* __restrict__ fb,
    unsigned short* __restrict__ fusedB, float* __restrict__ ymean)
{
    __shared__ __align__(16) unsigned int Atile4[4 * LPXC * 60 + 4];   // 78,736 B
    int flat = blockIdx.x + 4 * (blockIdx.y + 48 * blockIdx.z);
    int tau = (flat & 7) * 96 + (flat >> 3);       // XCD-contiguous remap (768 % 8 == 0, bijective)
    int wx = tau & 3, hy = (tau >> 2) % 48, bb = tau / 192;
    int h0 = hy * 2;
    int w0 = wx * TPX;
    int tid = threadIdx.x;
    int wid = tid >> 6;
    int l   = tid & 63;

    {
        int hh = h0 - 1 + wid;
        hh = hh < 0 ? -hh : (hh >= H_ ? 2 * H_ - 2 - hh : hh);
        const char* gsrc = (const char*)(abf + ((size_t)(bb * H_ + hh) * APX + w0) * 60);
        char* lbase = (char*)Atile4 + wid * LPLANB;
#pragma unroll
        for (int i = 0; i < 19; i++)
            gload16(gsrc + (i * 64 + l) * 16, lbase + i * 1024);
        if (l < 14) gload16(gsrc + (1216 + l) * 16, lbase + 1216 * 16);
    }
    __syncthreads();

    int row = wid >> 1;
    int ch  = wid & 1;
    int li = l & 15, lg = l >> 4;

    const short8* __restrict__ wp8 = reinterpret_cast<const short8*>(wpack);

    f32x4 acc[NPT][2];
    float bv0 = fb[(ch * 2 + 0) * 16 + li];
    float bv1 = fb[(ch * 2 + 1) * 16 + li];
#pragma unroll
    for (int pt = 0; pt < NPT; pt++) {
        acc[pt][0] = (f32x4){bv0, bv0, bv0, bv0};
        acc[pt][1] = (f32x4){bv1, bv1, bv1, bv1};
    }

    const char* Abase = (const char*)Atile4;
    short8 bc0 = wp8[0 * 256 + (ch * 2 + 0) * 64 + l];
    short8 bc1 = wp8[0 * 256 + (ch * 2 + 1) * 64 + l];
#pragma unroll
    for (int step = 0; step < 36; step++) {
        int kh = step / 12, kw2 = (step / 4) % 3, kblk = step & 3;
        short8 bn0 = bc0, bn1 = bc1;
        if (step < 35) {
            bn0 = wp8[(step + 1) * 256 + (ch * 2 + 0) * 64 + l];
            bn1 = wp8[(step + 1) * 256 + (ch * 2 + 1) * 64 + l];
        }
        int rbase = (row + kh) * LPLANB + kblk * 64 + lg * 16 + (kw2 + li) * LROWB;
        short8 av[NPT];
#pragma unroll
        for (int pt = 0; pt < NPT; pt++)
            av[pt] = *reinterpret_cast<const short8*>(Abase + rbase + pt * (16 * LROWB));
#pragma unroll
        for (int pt = 0; pt < NPT; pt++) {
            acc[pt][0] = __builtin_amdgcn_mfma_f32_16x16x32_bf16(av[pt], bc0, acc[pt][0], 0, 0, 0);
            acc[pt][1] = __builtin_amdgcn_mfma_f32_16x16x32_bf16(av[pt], bc1, acc[pt][1], 0, 0, 0);
        }
        bc0 = bn0; bc1 = bn1;
    }

    int h = h0 + row;
#pragma unroll
    for (int j = 0; j < 2; j++) {
        int co = (ch * 2 + j) * 16 + li;
        unsigned short* ob = fusedB + ((size_t)(bb * C_ + co) * H_ + h) * W_ + w0 + lg * 4;
#pragma unroll
        for (int pt = 0; pt < NPT; pt++) {
            u16x4 pk;
#pragma unroll
            for (int rg = 0; rg < 4; rg++) pk[rg] = (unsigned short)bf16rne(acc[pt][j][rg]);
            *reinterpret_cast<u16x4*>(ob + pt * 16) = pk;
        }
    }
    float s0 = 0.f, s1 = 0.f;
#pragma unroll
    for (int pt = 0; pt < NPT; pt++)
#pragma unroll
        for (int rg = 0; rg < 4; rg++) { s0 += acc[pt][0][rg]; s1 += acc[pt][1][rg]; }
    s0 += __shfl_xor(s0, 16); s0 += __shfl_xor(s0, 32);
    s1 += __shfl_xor(s1, 16); s1 += __shfl_xor(s1, 32);
    if (lg == 0) {
        atomicAdd(&ymean[bb * C_ + (ch * 2 + 0) * 16 + li], s0);
        atomicAdd(&ymean[bb * C_ + (ch * 2 + 1) * 16 + li], s1);
    }
}

// ---------- 12. SE MLP (ymean holds SUMS; scale by 1/HW) ----------
__global__ __launch_bounds__(256) void k_se(const float* __restrict__ ymean,
    const float* __restrict__ w1, const float* __restrict__ w2, float* __restrict__ scale)
{
    __shared__ float h4[B_ * 4];
    int t = threadIdx.x;
    const float invHW = 1.f / (float)HW;
    if (t < B_ * 4) {
        int b = t >> 2, o = t & 3;
        float a = 0.f;
        for (int c = 0; c < C_; c++) a += w1[o * C_ + c] * (ymean[b * C_ + c] * invHW);
        h4[b * 4 + o] = fmaxf(a, 0.f);
    }
    __syncthreads();
    {
        int b = t >> 6, c = t & 63;
        float a = 0.f;
        for (int o = 0; o < 4; o++) a += w2[c * 4 + o] * h4[b * 4 + o];
        scale[t] = sigm(a);
    }
}

// ---------- 13. final: x = elu(bf16(fused) * scale), 8 px/thread ----------
__global__ __launch_bounds__(256) void k_final(const unsigned short* __restrict__ fusedB,
    const float* __restrict__ scale, float* __restrict__ out)
{
    int idx8 = blockIdx.x * 256 + threadIdx.x;     // B_*C_*HW/8 = 983,040 -> 3840 blocks
    int bc = idx8 / (HW / 8);
    float sc = scale[bc];
    short8 v = ((const short8*)fusedB)[idx8];
    float4 o0, o1;
    o0.x = elu1(bf2f((unsigned short)v[0]) * sc);
    o0.y = elu1(bf2f((unsigned short)v[1]) * sc);
    o0.z = elu1(bf2f((unsigned short)v[2]) * sc);
    o0.w = elu1(bf2f((unsigned short)v[3]) * sc);
    o1.x = elu1(bf2f((unsigned short)v[4]) * sc);
    o1.y = elu1(bf2f((unsigned short)v[5]) * sc);
    o1.z = elu1(bf2f((unsigned short)v[6]) * sc);
    o1.w = elu1(bf2f((unsigned short)v[7]) * sc);
    ((float4*)out)[idx8 * 2 + 0] = o0;
    ((float4*)out)[idx8 * 2 + 1] = o1;
}

extern "C" void kernel_launch(void* const* d_in, const int* in_sizes, int n_in,
                              void* d_out, int out_size, void* d_ws, size_t ws_size,
                              hipStream_t stream)
{
    const float* left   = (const float*)d_in[0];
    const float* right  = (const float*)d_in[1];
    const float* directs= (const float*)d_in[2];
    const float* qw     = (const float*)d_in[3];
    const float* q_g    = (const float*)d_in[4];
    const float* q_b    = (const float*)d_in[5];
    const float* kw     = (const float*)d_in[6];
    const float* k_g    = (const float*)d_in[7];
    const float* k_b    = (const float*)d_in[8];
    const float* gaw1   = (const float*)d_in[9];
    const float* gab1   = (const float*)d_in[10];
    const float* gaw2   = (const float*)d_in[11];
    const float* gab2   = (const float*)d_in[12];
    const float* law    = (const float*)d_in[13];
    const float* lab    = (const float*)d_in[14];
    const float* lag    = (const float*)d_in[15];
    const float* labb   = (const float*)d_in[16];
    const float* afw1   = (const float*)d_in[17];
    const float* afb1   = (const float*)d_in[18];
    const float* afw2   = (const float*)d_in[19];
    const float* afb2   = (const float*)d_in[20];
    const float* rdww   = (const float*)d_in[21];
    const float* rdwb   = (const float*)d_in[22];
    const float* rpww   = (const float*)d_in[23];
    const float* rpwb   = (const float*)d_in[24];
    const float* fuw    = (const float*)d_in[25];
    const float* fub    = (const float*)d_in[26];
    const float* sew1   = (const float*)d_in[27];
    const float* sew2   = (const float*)d_in[28];

    // workspace layout (floats), peak 15,852,544 = 63.4 MB (proven footprint).
    //  abf   [0 .. 7,418,880)            written by k_prep (L-part) + k_rpw (N-part); read by fused_mfma
    //  kraw  [7,418,880 .. 9,384,960)    = lraw after km
    //  km    [9,384,960 .. 9,507,840)
    //  qraw  [9,507,840 .. 11,473,920)   dead after conv_la/rowmean
    //  vol   [9,507,840 .. 15,406,080)   over dead qraw (written by k_vol, dead after k_dw)
    //  fusedB(bf16) [7,418,880 .. 11,351,040) over dead kraw/km/qraw/vol-start (at fused_mfma time)
    //  weights/wpack [15,406,080 .. 15,447,296)  never overlapped
    //  smal  [15,851,520 .. 15,852,544)
    float* ws    = (float*)d_ws;
    unsigned int* abf = (unsigned int*)(ws + 0);
    float* kraw  = ws + 7418880;
    float* lraw  = kraw;
    float* km    = ws + 9384960;
    float* qraw  = ws + 9507840;
    float* vol   = ws + 9507840;
    unsigned short* fusedB = (unsigned short*)(ws + 7418880);
    float* qwp   = ws + 15406080;         // 1024
    float* kwp   = ws + 15407104;         // 1024
    float* lawp  = ws + 15408128;         // 2304
    unsigned short* wpack = (unsigned short*)(ws + 15410432);  // 36,864 float-slots
    float* smal  = ws + 15851520;

    float* stQ   = smal + 0;              // 64 (stK = stQ+64 contiguous for k_gn_stats2)
    float* stL   = smal + 128;
    float* gp    = smal + 192;
    float* gbias = smal + 256;
    float* ymean = smal + 320;
    float* scal  = smal + 576;

    float* xout  = (float*)d_out;            // 7,864,320
    float* ncost = xout + 7864320;           // 5,898,240 (k_dw scratch, in-place k_rpw)

    k_wprep<<<37, 256, 0, stream>>>(qw, kw, law, fuw, qwp, kwp, lawp, wpack, ymean);
    k_conv_qk<<<240, 256, 0, stream>>>(left, right, qwp, kwp, qraw, kraw);
    k_gn_stats2<<<64, 256, 0, stream>>>(qraw, kraw, stQ);
    k_gn_apply<<<1920, 256, 0, stream>>>(qraw, stQ, q_g, q_b);
    k_km<<<480, 256, 0, stream>>>(kraw, stQ + 64, k_g, k_b, km);
    k_rowmean<<<64, 256, 0, stream>>>(qraw, gp);
    k_gfeat<<<1, 64, 0, stream>>>(gp, gaw1, gab1, gaw2, gab2, afw1, afb1, gbias);
    k_conv_la<<<480, 256, 0, stream>>>(qraw, lawp, lab, lraw);
    k_gn_stats<<<32, 256, 0, stream>>>(lraw, stL);
    k_vol<<<384, 320, 0, stream>>>(lraw, stL, lag, labb, gbias, afw1, afw2, afb2, km, directs, vol);
    k_dw<<<5760, 256, 0, stream>>>(vol, rdww, rdwb, ncost);
    k_prep<<<483, 256, 0, stream>>>(left, abf);
    k_rpw<<<480, 256, 0, stream>>>(ncost, rpww, rpwb, abf);
    k_fused_mfma<<<dim3(4, 48, 4), 256, 0, stream>>>(abf, wpack, fub, fusedB, ymean);
    k_se<<<1, 256, 0, stream>>>(ymean, sew1, sew2, scal);
    k_final<<<3840, 256, 0, stream>>>(fusedB, scal, xout);
}

// Round 14
// 236.790 us; speedup vs baseline: 1.0472x; 1.0472x over previous
//
#include <hip/hip_runtime.h>
#include <math.h>

// ---- problem constants ----
static constexpr int B_  = 4;
static constexpr int C_  = 64;
static constexpr int H_  = 96;
static constexpr int W_  = 320;
static constexpr int HW  = H_ * W_;          // 30720
static constexpr int RCH = 16;               // RC = C/4
static constexpr int D_  = 48;
static constexpr int NG  = 8;                // groupnorm groups
static constexpr int CPG = RCH / NG;         // 2 channels per group
static constexpr float EPS_ = 1e-5f;
static constexpr int APX = 322;              // abf padded px count (w = -1..320)

typedef __attribute__((ext_vector_type(8))) short short8;
typedef __attribute__((ext_vector_type(4))) float f32x4;
typedef __attribute__((ext_vector_type(4))) unsigned int u32x4;
typedef __attribute__((ext_vector_type(4))) unsigned short u16x4;

__device__ __forceinline__ float elu1(float x) { return x > 0.f ? x : __expf(x) - 1.f; }
__device__ __forceinline__ float sigm(float x) { return 1.f / (1.f + __expf(-x)); }
__device__ __forceinline__ unsigned bf16rne(float f) {
    unsigned u = __builtin_bit_cast(unsigned, f);
    u += 0x7fffu + ((u >> 16) & 1u);
    return u >> 16;
}
__device__ __forceinline__ float bf2f(unsigned short u) {
    unsigned v = ((unsigned)u) << 16;
    return __builtin_bit_cast(float, v);
}
__device__ __forceinline__ void gload16(const void* g, void* l) {
    __builtin_amdgcn_global_load_lds((const __attribute__((address_space(1))) unsigned int*)g,
                                     (__attribute__((address_space(3))) unsigned int*)l, 16, 0, 0);
}

// ---------- 0. merged weight prep: blocks 0..35 = MFMA wpack, block 36 = conv repack + ymean zero ----------
__global__ __launch_bounds__(256) void k_wprep(
    const float* __restrict__ qw, const float* __restrict__ kw, const float* __restrict__ law,
    const float* __restrict__ fw,
    float* __restrict__ qwp, float* __restrict__ kwp, float* __restrict__ lawp,
    unsigned short* __restrict__ wpack, float* __restrict__ ymean)
{
    int bi = blockIdx.x;
    int t = threadIdx.x;
    if (bi == 36) {
        if (t < B_ * C_) ymean[t] = 0.f;
        for (int i = t; i < RCH * C_; i += 256) {
            int c = i >> 4, r = i & 15;
            qwp[i] = qw[r * C_ + c];
            kwp[i] = kw[r * C_ + c];
        }
        for (int i = t; i < RCH * RCH * 9; i += 256) {
            int co = i & 15, rest = i >> 4;   // rest = ci*9 + tap
            int ci = rest / 9, tap = rest % 9;
            lawp[i] = law[(co * RCH + ci) * 9 + tap];
        }
        return;
    }
    int tap = bi >> 2, kblk = bi & 3;
    int kh = tap / 3, kw2 = tap % 3;
    int ct = t >> 6, l = t & 63;
    int co = ct * 16 + (l & 15);
    int ci0 = kblk * 32 + ((l >> 4) & 3) * 8;
    unsigned short v[8];
#pragma unroll
    for (int j = 0; j < 8; j++) {
        int ci = ci0 + j;
        float f = (ci < 112) ? fw[((size_t)(co * 112 + ci)) * 9 + kh * 3 + kw2] : 0.f;
        v[j] = (unsigned short)bf16rne(f);
    }
    *reinterpret_cast<short8*>(wpack + ((size_t)bi * 256 + t) * 8) = *reinterpret_cast<short8*>(v);
}

// ---------- 1. 1x1 conv: left->qraw, right->kraw. SGPR weights, 4px/thread float4, full unroll ----------
__global__ __launch_bounds__(256) void k_conv_qk(
    const float* __restrict__ left, const float* __restrict__ right,
    const float* __restrict__ qwp, const float* __restrict__ kwp,
    float* __restrict__ qraw, float* __restrict__ kraw)
{
    int idx = blockIdx.x * 256 + threadIdx.x;      // 240*256 threads, 4 px each
    int half = idx / (B_ * HW / 4);                // 0 = q (left), 1 = k (right); block-uniform
    int r0 = idx - half * (B_ * HW / 4);
    int b = r0 / (HW / 4), p4 = r0 - b * (HW / 4);
    int p = p4 * 4;
    const float* src = (half ? right : left) + (size_t)b * C_ * HW + p;
    const float* wp  = half ? kwp : qwp;
    float* dst = (half ? kraw : qraw) + (size_t)b * RCH * HW + p;
    float4 acc[RCH];
#pragma unroll
    for (int r = 0; r < RCH; r++) acc[r] = make_float4(0.f, 0.f, 0.f, 0.f);
#pragma unroll
    for (int c = 0; c < C_; c++) {                 // 64 independent 16B loads pipeline
        float4 v = *reinterpret_cast<const float4*>(src + (size_t)c * HW);
        const float* wrow = wp + c * RCH;          // uniform -> s_load operands
#pragma unroll
        for (int r = 0; r < RCH; r++) {
            acc[r].x += v.x * wrow[r];
            acc[r].y += v.y * wrow[r];
            acc[r].z += v.z * wrow[r];
            acc[r].w += v.w * wrow[r];
        }
    }
#pragma unroll
    for (int r = 0; r < RCH; r++)
        *reinterpret_cast<float4*>(dst + (size_t)r * HW) = acc[r];
}

// ---------- 2. group-norm stats for q AND k in one launch: blocks 0..31 q, 32..63 k ----------
__global__ __launch_bounds__(256) void k_gn_stats2(const float* __restrict__ qsrc,
    const float* __restrict__ ksrc, float* __restrict__ stats)
{
    int z = blockIdx.x;
    const float* src = (z < 32) ? qsrc : ksrc;
    int zz = (z < 32) ? z : z - 32;
    int b = zz / NG, g = zz % NG;
    const float4* base = (const float4*)(src + ((size_t)b * RCH + g * CPG) * HW);
    float s = 0.f, ss = 0.f;
    for (int i = threadIdx.x; i < CPG * HW / 4; i += 256) {
        float4 v = base[i];
        s  += v.x + v.y + v.z + v.w;
        ss += v.x * v.x + v.y * v.y + v.z * v.z + v.w * v.w;
    }
    __shared__ float rs[256], rq[256];
    rs[threadIdx.x] = s; rq[threadIdx.x] = ss; __syncthreads();
    for (int off = 128; off > 0; off >>= 1) {
        if (threadIdx.x < off) { rs[threadIdx.x] += rs[threadIdx.x + off]; rq[threadIdx.x] += rq[threadIdx.x + off]; }
        __syncthreads();
    }
    if (threadIdx.x == 0) {
        float inv = 1.f / (float)(CPG * HW);
        float m = rs[0] * inv;
        float var = rq[0] * inv - m * m;
        stats[z * 2 + 0] = m;
        stats[z * 2 + 1] = rsqrtf(var + EPS_);
    }
}

// ---------- 2b. group-norm stats (single tensor, for lraw) ----------
__global__ __launch_bounds__(256) void k_gn_stats(const float* __restrict__ src, float* __restrict__ stats)
{
    int b = blockIdx.x / NG, g = blockIdx.x % NG;
    const float4* base = (const float4*)(src + ((size_t)b * RCH + g * CPG) * HW);
    float s = 0.f, ss = 0.f;
    for (int i = threadIdx.x; i < CPG * HW / 4; i += 256) {
        float4 v = base[i];
        s  += v.x + v.y + v.z + v.w;
        ss += v.x * v.x + v.y * v.y + v.z * v.z + v.w * v.w;
    }
    __shared__ float rs[256], rq[256];
    rs[threadIdx.x] = s; rq[threadIdx.x] = ss; __syncthreads();
    for (int off = 128; off > 0; off >>= 1) {
        if (threadIdx.x < off) { rs[threadIdx.x] += rs[threadIdx.x + off]; rq[threadIdx.x] += rq[threadIdx.x + off]; }
        __syncthreads();
    }
    if (threadIdx.x == 0) {
        float inv = 1.f / (float)(CPG * HW);
        float m = rs[0] * inv;
        float var = rq[0] * inv - m * m;
        stats[blockIdx.x * 2 + 0] = m;
        stats[blockIdx.x * 2 + 1] = rsqrtf(var + EPS_);
    }
}

// ---------- 3. GN apply + elu, in place (for q), float4 ----------
__global__ __launch_bounds__(256) void k_gn_apply(float* __restrict__ x, const float* __restrict__ stats,
    const float* __restrict__ gam, const float* __restrict__ bet)
{
    int idx4 = blockIdx.x * 256 + threadIdx.x;     // B_*RCH*HW/4 threads
    int b = idx4 / (RCH * HW / 4);
    int rc = (idx4 / (HW / 4)) % RCH;
    int g = rc >> 1;
    float m = stats[(b * NG + g) * 2], is = stats[(b * NG + g) * 2 + 1];
    float ga = gam[rc] * is, be = bet[rc] - m * is * gam[rc];
    float4 v = ((const float4*)x)[idx4];
    v.x = elu1(v.x * ga + be); v.y = elu1(v.y * ga + be);
    v.z = elu1(v.z * ga + be); v.w = elu1(v.w * ga + be);
    ((float4*)x)[idx4] = v;
}

// ---------- 4. km = mean over channels of elu(GN(kraw)) ----------
__global__ __launch_bounds__(256) void k_km(const float* __restrict__ kraw, const float* __restrict__ stats,
    const float* __restrict__ gam, const float* __restrict__ bet, float* __restrict__ km)
{
    int idx = blockIdx.x * 256 + threadIdx.x;      // B_*HW
    int b = idx / HW, p = idx - b * HW;
    float s = 0.f;
#pragma unroll
    for (int rc = 0; rc < RCH; rc++) {
        int g = rc >> 1;
        float m = stats[(b * NG + g) * 2], is = stats[(b * NG + g) * 2 + 1];
        float v = (kraw[((size_t)b * RCH + rc) * HW + p] - m) * is * gam[rc] + bet[rc];
        s += elu1(v);
    }
    km[idx] = s * (1.f / (float)RCH);
}

// ---------- 5. per-row mean over HW (gp), float4 ----------
__global__ __launch_bounds__(256) void k_rowmean(const float* __restrict__ src, float* __restrict__ out)
{
    const float4* base = (const float4*)(src + (size_t)blockIdx.x * HW);
    float s = 0.f;
    for (int p = threadIdx.x; p < HW / 4; p += 256) {
        float4 v = base[p];
        s += v.x + v.y + v.z + v.w;
    }
    __shared__ float red[256];
    red[threadIdx.x] = s; __syncthreads();
    for (int off = 128; off > 0; off >>= 1) {
        if (threadIdx.x < off) red[threadIdx.x] += red[threadIdx.x + off];
        __syncthreads();
    }
    if (threadIdx.x == 0) out[blockIdx.x] = red[0] * (1.f / (float)HW);
}

// ---------- 6. gfeat MLP + fold into attn-hidden bias: gbias[b,o] (gp holds MEANS) ----------
__global__ __launch_bounds__(64) void k_gfeat(const float* __restrict__ gp,
    const float* __restrict__ gaw1, const float* __restrict__ gab1,
    const float* __restrict__ gaw2, const float* __restrict__ gab2,
    const float* __restrict__ afw1, const float* __restrict__ afb1,
    float* __restrict__ gbias)
{
    __shared__ float g1[B_ * 8], gf[B_ * RCH];
    int t = threadIdx.x;
    if (t < B_ * 8) {
        int b = t >> 3, o = t & 7;
        float a = gab1[o];
        for (int i = 0; i < RCH; i++) a += gaw1[o * RCH + i] * gp[b * RCH + i];
        g1[b * 8 + o] = elu1(a);
    }
    __syncthreads();
    {
        int b = t >> 4, o = t & 15;
        float a = gab2[o];
        for (int i = 0; i < 8; i++) a += gaw2[o * 8 + i] * g1[b * 8 + i];
        gf[t] = a;
    }
    __syncthreads();
    {
        int b = t >> 4, o = t & 15;
        float a = afb1[o];
        for (int i = 0; i < RCH; i++) a += afw1[o * 2 * RCH + i] * gf[b * RCH + i];
        gbias[t] = a;
    }
}

// ---------- 7. 3x3 conv q -> lraw (zero pad, bias). SGPR weights, full unroll ----------
__global__ __launch_bounds__(256) void k_conv_la(const float* __restrict__ q,
    const float* __restrict__ lawp, const float* __restrict__ lab, float* __restrict__ lraw)
{
    int idx = blockIdx.x * 256 + threadIdx.x;      // B_*HW
    int b = idx / HW, p = idx - b * HW;
    int h = p / W_, w = p - h * W_;
    float acc[RCH];
#pragma unroll
    for (int co = 0; co < RCH; co++) acc[co] = lab[co];
#pragma unroll
    for (int ci = 0; ci < RCH; ci++) {
        const float* qb = q + ((size_t)b * RCH + ci) * HW;
#pragma unroll
        for (int kh = 0; kh < 3; kh++) {
            int hh = h + kh - 1;
            if (hh < 0 || hh >= H_) continue;
            float a0 = (w - 1 >= 0) ? qb[hh * W_ + w - 1] : 0.f;
            float a1 = qb[hh * W_ + w];
            float a2 = (w + 1 < W_) ? qb[hh * W_ + w + 1] : 0.f;
            const float* wp0 = lawp + (ci * 9 + kh * 3) * RCH;   // uniform -> s_load
#pragma unroll
            for (int co = 0; co < RCH; co++)
                acc[co] += a0 * wp0[co] + a1 * wp0[RCH + co] + a2 * wp0[2 * RCH + co];
        }
    }
#pragma unroll
    for (int co = 0; co < RCH; co++) lraw[((size_t)b * RCH + co) * HW + p] = acc[co];
}

// ---------- 8. fused vol: one block per (b,h) row, km row + weights staged in LDS (r14: revert to r12) ----------
__global__ __launch_bounds__(320) void k_vol(const float* __restrict__ lraw,
    const float* __restrict__ stats, const float* __restrict__ lg, const float* __restrict__ lb,
    const float* __restrict__ gbias, const float* __restrict__ afw1,
    const float* __restrict__ afw2, const float* __restrict__ afb2,
    const float* __restrict__ km, const float* __restrict__ directs, float* __restrict__ vol)
{
    __shared__ float w1[RCH * 2 * RCH];   // 512
    __shared__ float w2[D_ * RCH];        // 768
    __shared__ float b2[D_];
    __shared__ float kms[W_];
    int blk = blockIdx.x;                 // B_*H_ = 384
    int b = blk / H_, h = blk - b * H_;
    int t = threadIdx.x;                  // 0..319 = w
    for (int i = t; i < RCH * 2 * RCH; i += 320) w1[i] = afw1[i];
    for (int i = t; i < D_ * RCH; i += 320) w2[i] = afw2[i];
    if (t < D_) b2[t] = afb2[t];
    kms[t] = km[(size_t)b * HW + h * W_ + t];
    __syncthreads();
    int w = t, p = h * W_ + w;
    float lf[RCH];
#pragma unroll
    for (int rc = 0; rc < RCH; rc++) {
        int g = rc >> 1;
        float m = stats[(b * NG + g) * 2], is = stats[(b * NG + g) * 2 + 1];
        lf[rc] = elu1((lraw[((size_t)b * RCH + rc) * HW + p] - m) * is * lg[rc] + lb[rc]);
    }
    float hid[RCH];
#pragma unroll
    for (int o = 0; o < RCH; o++) {
        float a = gbias[b * RCH + o];
#pragma unroll
        for (int i = 0; i < RCH; i++) a += w1[o * 2 * RCH + RCH + i] * lf[i];
        hid[o] = elu1(a);
    }
    float dir = directs[b];
    for (int d = 0; d < D_; d++) {
        float a = b2[d];
#pragma unroll
        for (int o = 0; o < RCH; o++) a += w2[d * RCH + o] * hid[o];
        float s = sigm(a);
        float shift = ((float)d / 160.f) * dir * (float)(W_ - 1);
        float pos = (float)w + shift;
        float x0 = floorf(pos);
        float f = pos - x0;
        float c0 = fminf(fmaxf(x0, 0.f), (float)(W_ - 1));
        float c1 = fminf(fmaxf(x0 + 1.f, 0.f), (float)(W_ - 1));
        int i0 = (int)c0, i1 = (int)c1;
        float wv = kms[i0] * (1.f - f) + kms[i1] * f;
        vol[((size_t)(b * D_ + d)) * HW + p] = wv * s;
    }
}

// ---------- 9. depthwise 3x3 + elu, 4 px/thread (writes into ncost region as scratch) ----------
__global__ __launch_bounds__(256) void k_dw(const float* __restrict__ vol,
    const float* __restrict__ wgt, const float* __restrict__ bias, float* __restrict__ dwout)
{
    int idx = blockIdx.x * 256 + threadIdx.x;      // B_*D_*HW/4
    int p4 = idx % (HW / 4);
    int d  = (idx / (HW / 4)) % D_;
    int b  = idx / (D_ * HW / 4);
    int h = p4 / (W_ / 4), w = (p4 % (W_ / 4)) * 4;
    const float* vb = vol + ((size_t)(b * D_ + d)) * HW;
    float wz[9];
#pragma unroll
    for (int i = 0; i < 9; i++) wz[i] = wgt[d * 9 + i];
    float bv = bias[d];
    float acc[4] = {bv, bv, bv, bv};
#pragma unroll
    for (int r = 0; r < 3; r++) {
        int hh = h + r - 1;
        if (hh < 0 || hh >= H_) continue;
        const float* row = vb + hh * W_;
        float4 c = *(const float4*)(row + w);
        float in6[6];
        in6[0] = (w > 0) ? row[w - 1] : 0.f;
        in6[1] = c.x; in6[2] = c.y; in6[3] = c.z; in6[4] = c.w;
        in6[5] = (w + 4 < W_) ? row[w + 4] : 0.f;
#pragma unroll
        for (int j = 0; j < 4; j++)
            acc[j] += in6[j] * wz[r * 3] + in6[j + 1] * wz[r * 3 + 1] + in6[j + 2] * wz[r * 3 + 2];
    }
    float4 o;
    o.x = elu1(acc[0]); o.y = elu1(acc[1]); o.z = elu1(acc[2]); o.w = elu1(acc[3]);
    ((float4*)dwout)[idx] = o;
}

// ---------- 9b. prep: abf[b][h][322][120ci] bf16 — left channels (dw 0..31) + zero pad (dw 56..59) ----------
__global__ __launch_bounds__(256) void k_prep(const float* __restrict__ left, unsigned int* __restrict__ abf)
{
    int idx = blockIdx.x * 256 + threadIdx.x;      // B_*H_*APX = 123,648 exactly
    int px = idx % APX;
    int bh = idx / APX;
    int b = bh / H_, h = bh % H_;
    int w = px - 1;
    w = w < 0 ? -w : (w >= W_ ? 2 * W_ - 2 - w : w);
    const float* src = left + (size_t)b * C_ * HW + h * W_ + w;
    unsigned int* dst = abf + (size_t)idx * 60;
#pragma unroll
    for (int q4 = 0; q4 < 8; q4++) {
        u32x4 t;
#pragma unroll
        for (int z = 0; z < 4; z++) {
            int ci = (q4 * 4 + z) * 2;
            float f0 = src[(size_t)ci * HW];
            float f1 = src[(size_t)(ci + 1) * HW];
            t[z] = bf16rne(f0) | (bf16rne(f1) << 16);
        }
        *reinterpret_cast<u32x4*>(dst + q4 * 4) = t;
    }
    *reinterpret_cast<u32x4*>(dst + 56) = (u32x4){0u, 0u, 0u, 0u};
}

// ---------- 10. 1x1 48->48 + softmax, IN PLACE on ncost; LDS weights (r14: revert to r12); writes abf ----------
__global__ __launch_bounds__(256) void k_rpw(float* __restrict__ ncost,
    const float* __restrict__ wgt, const float* __restrict__ bias,
    unsigned int* __restrict__ abf)
{
    __shared__ float wr[D_ * D_];   // 2304
    __shared__ float bs[D_];
    for (int i = threadIdx.x; i < D_ * D_; i += 256) wr[i] = wgt[i];
    if (threadIdx.x < D_) bs[threadIdx.x] = bias[threadIdx.x];
    __syncthreads();
    int idx = blockIdx.x * 256 + threadIdx.x;      // B_*HW
    int b = idx / HW, p = idx - b * HW;
    int h = p / W_, w = p - h * W_;
    float v[D_];
#pragma unroll
    for (int i = 0; i < D_; i++) v[i] = ncost[((size_t)(b * D_ + i)) * HW + p];
    float cst[D_];
    float mx = -1e30f;
#pragma unroll
    for (int d = 0; d < D_; d++) {
        float a = bs[d];
        const float4* wrow = (const float4*)&wr[d * D_];
#pragma unroll
        for (int i4 = 0; i4 < D_ / 4; i4++) {
            float4 wv = wrow[i4];
            a += wv.x * v[i4 * 4 + 0] + wv.y * v[i4 * 4 + 1]
               + wv.z * v[i4 * 4 + 2] + wv.w * v[i4 * 4 + 3];
        }
        cst[d] = a; mx = fmaxf(mx, a);
    }
    float s = 0.f;
#pragma unroll
    for (int d = 0; d < D_; d++) { float e = __expf(cst[d] - mx); cst[d] = e; s += e; }
    float inv = 1.f / s;
#pragma unroll
    for (int d = 0; d < D_; d++) {
        cst[d] *= inv;
        ncost[((size_t)(b * D_ + d)) * HW + p] = cst[d];
    }
    u32x4 pk[6];
#pragma unroll
    for (int q4 = 0; q4 < 6; q4++)
#pragma unroll
        for (int z = 0; z < 4; z++) {
            int d = (q4 * 4 + z) * 2;
            pk[q4][z] = bf16rne(cst[d]) | (bf16rne(cst[d + 1]) << 16);
        }
    size_t bh322 = (size_t)(b * H_ + h) * APX;
    unsigned int* dst = abf + (bh322 + (w + 1)) * 60 + 32;
#pragma unroll
    for (int q4 = 0; q4 < 6; q4++) *reinterpret_cast<u32x4*>(dst + q4 * 4) = pk[q4];
    if (w == 1 || w == W_ - 2) {
        unsigned int* dst2 = abf + (bh322 + (w == 1 ? 0 : APX - 1)) * 60 + 32;
#pragma unroll
        for (int q4 = 0; q4 < 6; q4++) *reinterpret_cast<u32x4*>(dst2 + q4 * 4) = pk[q4];
    }
}

// ---------- 11. fused 3x3 conv 112->64, reflect pad, bf16 MFMA implicit GEMM ----------
static constexpr int TPX    = 80;                  // output px per block
static constexpr int LPXC   = TPX + 2;             // 82 staged px per plane
static constexpr int LROWB  = 240;                 // bytes per px (120 bf16)
static constexpr int LPLANB = LPXC * LROWB;        // 19680 B per input row
static constexpr int NPT    = TPX / 16;            // 5 px-tiles per wave
__global__ __launch_bounds__(256, 1) void k_fused_mfma(
    const unsigned int* __restrict__ abf,
    const unsigned short* __restrict__ wpack, const float* __restrict__ fb,
    unsigned short* __restrict__ fusedB, float* __restrict__ ymean)
{
    __shared__ __align__(16) unsigned int Atile4[4 * LPXC * 60 + 4];   // 78,736 B
    int flat = blockIdx.x + 4 * (blockIdx.y + 48 * blockIdx.z);
    int tau = (flat & 7) * 96 + (flat >> 3);       // XCD-contiguous remap (768 % 8 == 0, bijective)
    int wx = tau & 3, hy = (tau >> 2) % 48, bb = tau / 192;
    int h0 = hy * 2;
    int w0 = wx * TPX;
    int tid = threadIdx.x;
    int wid = tid >> 6;
    int l   = tid & 63;

    {
        int hh = h0 - 1 + wid;
        hh = hh < 0 ? -hh : (hh >= H_ ? 2 * H_ - 2 - hh : hh);
        const char* gsrc = (const char*)(abf + ((size_t)(bb * H_ + hh) * APX + w0) * 60);
        char* lbase = (char*)Atile4 + wid * LPLANB;
#pragma unroll
        for (int i = 0; i < 19; i++)
            gload16(gsrc + (i * 64 + l) * 16, lbase + i * 1024);
        if (l < 14) gload16(gsrc + (1216 + l) * 16, lbase + 1216 * 16);
    }
    __syncthreads();

    int row = wid >> 1;
    int ch  = wid & 1;
    int li = l & 15, lg = l >> 4;

    const short8* __restrict__ wp8 = reinterpret_cast<const short8*>(wpack);

    f32x4 acc[NPT][2];
    float bv0 = fb[(ch * 2 + 0) * 16 + li];
    float bv1 = fb[(ch * 2 + 1) * 16 + li];
#pragma unroll
    for (int pt = 0; pt < NPT; pt++) {
        acc[pt][0] = (f32x4){bv0, bv0, bv0, bv0};
        acc[pt][1] = (f32x4){bv1, bv1, bv1, bv1};
    }

    const char* Abase = (const char*)Atile4;
    short8 bc0 = wp8[0 * 256 + (ch * 2 + 0) * 64 + l];
    short8 bc1 = wp8[0 * 256 + (ch * 2 + 1) * 64 + l];
#pragma unroll
    for (int step = 0; step < 36; step++) {
        int kh = step / 12, kw2 = (step / 4) % 3, kblk = step & 3;
        short8 bn0 = bc0, bn1 = bc1;
        if (step < 35) {
            bn0 = wp8[(step + 1) * 256 + (ch * 2 + 0) * 64 + l];
            bn1 = wp8[(step + 1) * 256 + (ch * 2 + 1) * 64 + l];
        }
        int rbase = (row + kh) * LPLANB + kblk * 64 + lg * 16 + (kw2 + li) * LROWB;
        short8 av[NPT];
#pragma unroll
        for (int pt = 0; pt < NPT; pt++)
            av[pt] = *reinterpret_cast<const short8*>(Abase + rbase + pt * (16 * LROWB));
#pragma unroll
        for (int pt = 0; pt < NPT; pt++) {
            acc[pt][0] = __builtin_amdgcn_mfma_f32_16x16x32_bf16(av[pt], bc0, acc[pt][0], 0, 0, 0);
            acc[pt][1] = __builtin_amdgcn_mfma_f32_16x16x32_bf16(av[pt], bc1, acc[pt][1], 0, 0, 0);
        }
        bc0 = bn0; bc1 = bn1;
    }

    int h = h0 + row;
#pragma unroll
    for (int j = 0; j < 2; j++) {
        int co = (ch * 2 + j) * 16 + li;
        unsigned short* ob = fusedB + ((size_t)(bb * C_ + co) * H_ + h) * W_ + w0 + lg * 4;
#pragma unroll
        for (int pt = 0; pt < NPT; pt++) {
            u16x4 pk;
#pragma unroll
            for (int rg = 0; rg < 4; rg++) pk[rg] = (unsigned short)bf16rne(acc[pt][j][rg]);
            *reinterpret_cast<u16x4*>(ob + pt * 16) = pk;
        }
    }
    float s0 = 0.f, s1 = 0.f;
#pragma unroll
    for (int pt = 0; pt < NPT; pt++)
#pragma unroll
        for (int rg = 0; rg < 4; rg++) { s0 += acc[pt][0][rg]; s1 += acc[pt][1][rg]; }
    s0 += __shfl_xor(s0, 16); s0 += __shfl_xor(s0, 32);
    s1 += __shfl_xor(s1, 16); s1 += __shfl_xor(s1, 32);
    if (lg == 0) {
        atomicAdd(&ymean[bb * C_ + (ch * 2 + 0) * 16 + li], s0);
        atomicAdd(&ymean[bb * C_ + (ch * 2 + 1) * 16 + li], s1);
    }
}

// ---------- 12. SE MLP (ymean holds SUMS; scale by 1/HW) ----------
__global__ __launch_bounds__(256) void k_se(const float* __restrict__ ymean,
    const float* __restrict__ w1, const float* __restrict__ w2, float* __restrict__ scale)
{
    __shared__ float h4[B_ * 4];
    int t = threadIdx.x;
    const float invHW = 1.f / (float)HW;
    if (t < B_ * 4) {
        int b = t >> 2, o = t & 3;
        float a = 0.f;
        for (int c = 0; c < C_; c++) a += w1[o * C_ + c] * (ymean[b * C_ + c] * invHW);
        h4[b * 4 + o] = fmaxf(a, 0.f);
    }
    __syncthreads();
    {
        int b = t >> 6, c = t & 63;
        float a = 0.f;
        for (int o = 0; o < 4; o++) a += w2[c * 4 + o] * h4[b * 4 + o];
        scale[t] = sigm(a);
    }
}

// ---------- 13. final: x = elu(bf16(fused) * scale), 8 px/thread ----------
__global__ __launch_bounds__(256) void k_final(const unsigned short* __restrict__ fusedB,
    const float* __restrict__ scale, float* __restrict__ out)
{
    int idx8 = blockIdx.x * 256 + threadIdx.x;     // B_*C_*HW/8 = 983,040 -> 3840 blocks
    int bc = idx8 / (HW / 8);
    float sc = scale[bc];
    short8 v = ((const short8*)fusedB)[idx8];
    float4 o0, o1;
    o0.x = elu1(bf2f((unsigned short)v[0]) * sc);
    o0.y = elu1(bf2f((unsigned short)v[1]) * sc);
    o0.z = elu1(bf2f((unsigned short)v[2]) * sc);
    o0.w = elu1(bf2f((unsigned short)v[3]) * sc);
    o1.x = elu1(bf2f((unsigned short)v[4]) * sc);
    o1.y = elu1(bf2f((unsigned short)v[5]) * sc);
    o1.z = elu1(bf2f((unsigned short)v[6]) * sc);
    o1.w = elu1(bf2f((unsigned short)v[7]) * sc);
    ((float4*)out)[idx8 * 2 + 0] = o0;
    ((float4*)out)[idx8 * 2 + 1] = o1;
}

extern "C" void kernel_launch(void* const* d_in, const int* in_sizes, int n_in,
                              void* d_out, int out_size, void* d_ws, size_t ws_size,
                              hipStream_t stream)
{
    const float* left   = (const float*)d_in[0];
    const float* right  = (const float*)d_in[1];
    const float* directs= (const float*)d_in[2];
    const float* qw     = (const float*)d_in[3];
    const float* q_g    = (const float*)d_in[4];
    const float* q_b    = (const float*)d_in[5];
    const float* kw     = (const float*)d_in[6];
    const float* k_g    = (const float*)d_in[7];
    const float* k_b    = (const float*)d_in[8];
    const float* gaw1   = (const float*)d_in[9];
    const float* gab1   = (const float*)d_in[10];
    const float* gaw2   = (const float*)d_in[11];
    const float* gab2   = (const float*)d_in[12];
    const float* law    = (const float*)d_in[13];
    const float* lab    = (const float*)d_in[14];
    const float* lag    = (const float*)d_in[15];
    const float* labb   = (const float*)d_in[16];
    const float* afw1   = (const float*)d_in[17];
    const float* afb1   = (const float*)d_in[18];
    const float* afw2   = (const float*)d_in[19];
    const float* afb2   = (const float*)d_in[20];
    const float* rdww   = (const float*)d_in[21];
    const float* rdwb   = (const float*)d_in[22];
    const float* rpww   = (const float*)d_in[23];
    const float* rpwb   = (const float*)d_in[24];
    const float* fuw    = (const float*)d_in[25];
    const float* fub    = (const float*)d_in[26];
    const float* sew1   = (const float*)d_in[27];
    const float* sew2   = (const float*)d_in[28];

    // workspace layout (floats), peak 15,852,544 = 63.4 MB (proven footprint).
    //  abf   [0 .. 7,418,880)            written by k_prep (L-part) + k_rpw (N-part); read by fused_mfma
    //  kraw  [7,418,880 .. 9,384,960)    = lraw after km
    //  km    [9,384,960 .. 9,507,840)
    //  qraw  [9,507,840 .. 11,473,920)   dead after conv_la/rowmean
    //  vol   [9,507,840 .. 15,406,080)   over dead qraw (written by k_vol, dead after k_dw)
    //  fusedB(bf16) [7,418,880 .. 11,351,040) over dead kraw/km/qraw/vol-start (at fused_mfma time)
    //  weights/wpack [15,406,080 .. 15,447,296)  never overlapped
    //  smal  [15,851,520 .. 15,852,544)
    float* ws    = (float*)d_ws;
    unsigned int* abf = (unsigned int*)(ws + 0);
    float* kraw  = ws + 7418880;
    float* lraw  = kraw;
    float* km    = ws + 9384960;
    float* qraw  = ws + 9507840;
    float* vol   = ws + 9507840;
    unsigned short* fusedB = (unsigned short*)(ws + 7418880);
    float* qwp   = ws + 15406080;         // 1024
    float* kwp   = ws + 15407104;         // 1024
    float* lawp  = ws + 15408128;         // 2304
    unsigned short* wpack = (unsigned short*)(ws + 15410432);  // 36,864 float-slots
    float* smal  = ws + 15851520;

    float* stQ   = smal + 0;              // 64 (stK = stQ+64 contiguous for k_gn_stats2)
    float* stL   = smal + 128;
    float* gp    = smal + 192;
    float* gbias = smal + 256;
    float* ymean = smal + 320;
    float* scal  = smal + 576;

    float* xout  = (float*)d_out;            // 7,864,320
    float* ncost = xout + 7864320;           // 5,898,240 (k_dw scratch, in-place k_rpw)

    k_wprep<<<37, 256, 0, stream>>>(qw, kw, law, fuw, qwp, kwp, lawp, wpack, ymean);
    k_conv_qk<<<240, 256, 0, stream>>>(left, right, qwp, kwp, qraw, kraw);
    k_gn_stats2<<<64, 256, 0, stream>>>(qraw, kraw, stQ);
    k_gn_apply<<<1920, 256, 0, stream>>>(qraw, stQ, q_g, q_b);
    k_km<<<480, 256, 0, stream>>>(kraw, stQ + 64, k_g, k_b, km);
    k_rowmean<<<64, 256, 0, stream>>>(qraw, gp);
    k_gfeat<<<1, 64, 0, stream>>>(gp, gaw1, gab1, gaw2, gab2, afw1, afb1, gbias);
    k_conv_la<<<480, 256, 0, stream>>>(qraw, lawp, lab, lraw);
    k_gn_stats<<<32, 256, 0, stream>>>(lraw, stL);
    k_vol<<<384, 320, 0, stream>>>(lraw, stL, lag, labb, gbias, afw1, afw2, afb2, km, directs, vol);
    k_dw<<<5760, 256, 0, stream>>>(vol, rdww, rdwb, ncost);
    k_prep<<<483, 256, 0, stream>>>(left, abf);
    k_rpw<<<480, 256, 0, stream>>>(ncost, rpww, rpwb, abf);
    k_fused_mfma<<<dim3(4, 48, 4), 256, 0, stream>>>(abf, wpack, fub, fusedB, ymean);
    k_se<<<1, 256, 0, stream>>>(ymean, sew1, sew2, scal);
    k_final<<<3840, 256, 0, stream>>>(fusedB, scal, xout);
}